// Round 3
// baseline (252.533 us; speedup 1.0000x reference)
//
#include <hip/hip_runtime.h>
#include <hip/hip_bf16.h>

typedef __attribute__((ext_vector_type(8))) short short8;
typedef __attribute__((ext_vector_type(4))) short s4v;
typedef __attribute__((ext_vector_type(2))) int   int2v;
typedef __attribute__((ext_vector_type(4))) float floatx4;

#define MFMA16(A,B,C) __builtin_amdgcn_mfma_f32_16x16x32_bf16(A,B,C,0,0,0)
// LDS-only drain: orders ds_write->ds_read without draining global prefetch (vmcnt)
#define LDS_FENCE() asm volatile("s_waitcnt lgkmcnt(0)" ::: "memory")

__device__ __forceinline__ short bf16bits(float x) {
    __hip_bfloat16 h = __float2bfloat16(x);
    return *(short*)&h;
}
__device__ __forceinline__ short8 cvt8(const float* p) {
    floatx4 a = *(const floatx4*)p;
    floatx4 b = *(const floatx4*)(p + 4);
    short8 r;
    r[0]=bf16bits(a.x); r[1]=bf16bits(a.y); r[2]=bf16bits(a.z); r[3]=bf16bits(a.w);
    r[4]=bf16bits(b.x); r[5]=bf16bits(b.y); r[6]=bf16bits(b.z); r[7]=bf16bits(b.w);
    return r;
}
// scaled variant for Q: folds 1/sqrt(d) * log2(e) so softmax is a bare v_exp_f32
__device__ __forceinline__ short8 cvt8s(const float* p) {
    constexpr float SCL2 = 0.125f * 1.44269504088896f;
    floatx4 a = *(const floatx4*)p;
    floatx4 b = *(const floatx4*)(p + 4);
    a *= SCL2; b *= SCL2;
    short8 r;
    r[0]=bf16bits(a.x); r[1]=bf16bits(a.y); r[2]=bf16bits(a.z); r[3]=bf16bits(a.w);
    r[4]=bf16bits(b.x); r[5]=bf16bits(b.y); r[6]=bf16bits(b.z); r[7]=bf16bits(b.w);
    return r;
}
// hardware packed f32->bf16 (RNE, identical rounding to __float2bfloat16)
__device__ __forceinline__ int pk2(float lo, float hi) {
    int r;
    asm("v_cvt_pk_bf16_f32 %0, %1, %2" : "=v"(r) : "v"(lo), "v"(hi));
    return r;
}
// direct global->LDS DMA, 16B/lane; LDS dest is wave-uniform base + lane*16
__device__ __forceinline__ void g2l16(const short* g, short* l) {
    __builtin_amdgcn_global_load_lds(
        (const __attribute__((address_space(1))) void*)g,
        (__attribute__((address_space(3))) void*)l, 16, 0, 0);
}

// ---- prologue (fused): V -> VT [h][d][s] bf16, and K -> K16 bf16 row-major ----
__global__ __launch_bounds__(256) void prep(const float* __restrict__ V,
                                            short* __restrict__ VT,
                                            const float* __restrict__ K,
                                            short* __restrict__ K16, int doK)
{
    __shared__ short tile[64 * 65];
    const int t  = threadIdx.x;
    const int h  = blockIdx.x >> 6;
    const int s0 = (blockIdx.x & 63) << 6;
    const float* src = V + ((size_t)h * 4096 + s0) * 64;
    const int r = t >> 4, dq = (t & 15) * 4;
#pragma unroll
    for (int pass = 0; pass < 4; ++pass) {
        const int s = pass * 16 + r;
        floatx4 f = *(const floatx4*)(src + s * 64 + dq);
        short* w = tile + s * 65 + dq;
        w[0] = bf16bits(f.x); w[1] = bf16bits(f.y);
        w[2] = bf16bits(f.z); w[3] = bf16bits(f.w);
    }
    __syncthreads();
    const int d = t >> 2, sc = (t & 3) * 16;
    short8 a, b;
#pragma unroll
    for (int j = 0; j < 8; ++j) a[j] = tile[(sc + j) * 65 + d];
#pragma unroll
    for (int j = 0; j < 8; ++j) b[j] = tile[(sc + 8 + j) * 65 + d];
    short* dst = VT + ((size_t)h * 64 + d) * 4096 + s0 + sc;
    *(short8*)dst       = a;
    *(short8*)(dst + 8) = b;
    if (doK) {
        const size_t base = (size_t)blockIdx.x * 4096 + (size_t)t * 16;
        *(short8*)(K16 + base)     = cvt8(K + base);
        *(short8*)(K16 + base + 8) = cvt8(K + base + 8);
    }
}

// ---- main: 4 waves x 32q; block x owns q-tiles {x, 63-x} sharing one K/V
// stream; double-buffered LDS staged by global_load_lds; 1 barrier / 64-key tile
template<bool KB16>
__global__ __launch_bounds__(256, 2)
void attn_fast(const float* __restrict__ Qg, const float* __restrict__ Kg,
               const short* __restrict__ K16g, const short* __restrict__ VTg,
               float* __restrict__ Og)
{
    constexpr int S = 4096, D = 64;

    __shared__ __align__(16) short lK[8192];   // 2 x (64 keys x 64 d), swizzled
    __shared__ __align__(16) short lV[8192];   // 2 x (64 d x 64 keys), swizzled
    __shared__ __align__(16) short lP[8192];   // per-wave 2048 (2 groups x 16q x 64k)

    const int tid = threadIdx.x;
    const int wv  = tid >> 6;
    const int ln  = tid & 63;
    const int ll  = ln & 15;
    const int qd  = ln >> 4;

    // block x in 0..31 handles q-tiles {63-x (waves 0-1), x (waves 2-3)}.
    // CU pairing (blocks c and c+256): durations {64-t, 33+t} tiles.
    const int c = blockIdx.x & 255;
    const int h = c & 15;
    const int t = c >> 4;                       // 0..15
    const int s = blockIdx.x >> 8;              // 0..1
    const int x = s ? (31 - t) : t;             // 0..31
    const int myTile = (wv < 2) ? (63 - x) : x;
    const int qrow   = myTile * 64 + (wv & 1) * 32;   // wave owns 32 q-rows
    const int kv_end = (64 - x) * 64;                 // shared K/V stream length
    const int wv_end = qrow + 32;

    const float* Qh  = Qg  + (size_t)h * S * D;
    const float* Kf  = Kg  + (size_t)h * S * D;
    const short* K16 = K16g + (size_t)h * S * D;
    const short* Vt  = VTg + (size_t)h * 64 * S;

    // Q fragments for both 16-row groups, pre-scaled
    short8 qA0, qA1, qB0, qB1;
    {
        const float* qp = Qh + (qrow + ll) * D + qd * 8;
        qA0 = cvt8s(qp);       qA1 = cvt8s(qp + 32);
        const float* qp2 = qp + 16 * D;
        qB0 = cvt8s(qp2);      qB1 = cvt8s(qp2 + 32);
    }

    floatx4 oA[4], oB[4], olA, olB;
#pragma unroll
    for (int dt = 0; dt < 4; ++dt) { oA[dt] = (floatx4){0.f,0.f,0.f,0.f}; oB[dt] = oA[dt]; }
    olA = (floatx4){0.f,0.f,0.f,0.f};
    olB = olA;

    short8 ones;
#pragma unroll
    for (int j = 0; j < 8; ++j) ones[j] = (short)0x3F80;  // bf16 1.0

    // ---- staging via global_load_lds: linear LDS dest, swizzle-inverted global src.
    // wave w, instr j covers LDS short8-slots [(w*2+j)*64, +64), lane ln -> slot+ln.
    // K slot decode (inverse of kdst swizzle): slot = h*256 + b*64 + sw,
    //   koct = (sw>>4)&3; kkey = h*32 + (b>>1)*16 + ((sw^(koct*5))&15); kd8 = ((b&1)<<2)|koct
    // V slot decode: voct = (sw>>4)&3; vd = b*16 + ((sw^(voct*5))&15); src = vd*S + h*32 + voct*8
    int kOff0, kOff1, vOff0, vOff1, kKey0, kKey1, kD80, kD81;
    {
#pragma unroll
        for (int j = 0; j < 2; ++j) {
            const int slot = (wv * 2 + j) * 64 + ln;
            const int hh = slot >> 8;
            const int bb = (slot >> 6) & 3;
            const int sw = slot & 63;
            const int ko = (sw >> 4) & 3;
            const int kkey = hh * 32 + (bb >> 1) * 16 + ((sw ^ (ko * 5)) & 15);
            const int kd8  = ((bb & 1) << 2) | ko;
            const int vo = ko;
            const int vd = bb * 16 + ((sw ^ (vo * 5)) & 15);
            const int kOf = kkey * 64 + kd8 * 8;
            const int vOf = vd * S + hh * 32 + vo * 8;
            if (j == 0) { kOff0 = kOf; vOff0 = vOf; kKey0 = kkey; kD80 = kd8; }
            else        { kOff1 = kOf; vOff1 = vOf; kKey1 = kkey; kD81 = kd8; }
        }
    }
    const int dstA = (wv * 2 + 0) * 512;   // short offset of this wave's chunk 0
    const int dstB = (wv * 2 + 1) * 512;   // chunk 1

    // fragment read block (lK / lV)
    const int rblk = ((ll | (qd << 4)) ^ (qd * 5));
    // P LDS (per 16-q group, per 32-key half): addr(k) = ll*32 + ((k>>3)^pswz)*8 + (k&7)
    const int pswz  = (ll >> 1) & 3;
    short* lPw = lP + wv * 2048;
    const int pw0 = ll * 32 + (((qd >> 1) ^ pswz) * 8) + (qd & 1) * 4;  // g=0 b64
    const int prd = ll * 32 + ((qd ^ pswz) * 8);                        // b128 read

    // ---- prologue: stage tile 0 into buffer 0 (kv_end >= 33 tiles always)
    short8 kApre, kBpre;
    g2l16(Vt + vOff0, lV + dstA);
    g2l16(Vt + vOff1, lV + dstB);
    if (KB16) {
        g2l16(K16 + kOff0, lK + dstA);
        g2l16(K16 + kOff1, lK + dstB);
    } else {
        *(short8*)(lK + dstA) = cvt8(Kf + (size_t)kKey0 * D + kD80 * 8);
        *(short8*)(lK + dstB) = cvt8(Kf + (size_t)kKey1 * D + kD81 * 8);
        kApre = cvt8(Kf + (size_t)(64 + kKey0) * D + kD80 * 8);
        kBpre = cvt8(Kf + (size_t)(64 + kKey1) * D + kD81 * 8);
    }

#define SOFTMAX_STORE(S0, S1, QG, BASE, KVH) do {                              \
    float p0_[4], p1_[4];                                                      \
    _Pragma("unroll")                                                          \
    for (int r = 0; r < 4; ++r) { p0_[r] = exp2f((S0)[r]); p1_[r] = exp2f((S1)[r]); } \
    if ((KVH) + 31 > (QG)) {                                                   \
        const int qg_ = (QG) + ll;                                             \
        const int k0_ = (KVH) + qd * 4, k1_ = k0_ + 16;                        \
        _Pragma("unroll")                                                      \
        for (int r = 0; r < 4; ++r) {                                          \
            if (k0_ + r > qg_) p0_[r] = 0.f;                                   \
            if (k1_ + r > qg_) p1_[r] = 0.f;                                   \
        }                                                                      \
    }                                                                          \
    *(int2v*)((BASE) + pw0)        = (int2v){pk2(p0_[0],p0_[1]), pk2(p0_[2],p0_[3])}; \
    *(int2v*)((BASE) + (pw0 ^ 16)) = (int2v){pk2(p1_[0],p1_[1]), pk2(p1_[2],p1_[3])}; \
} while (0)

    int bo = 0;
    for (int kv = 0; kv < kv_end; kv += 64) {
        // drains vmcnt (prev-iter g2l16 landed) + lgkm; all waves synced
        __syncthreads();
        const int nbo = bo ^ 4096;
        if (kv + 64 < kv_end) {            // stage next tile into other buffer
            g2l16(Vt + (kv + 64) + vOff0, lV + nbo + dstA);
            g2l16(Vt + (kv + 64) + vOff1, lV + nbo + dstB);
            if (KB16) {
                g2l16(K16 + (size_t)(kv + 64) * 64 + kOff0, lK + nbo + dstA);
                g2l16(K16 + (size_t)(kv + 64) * 64 + kOff1, lK + nbo + dstB);
            } else {
                *(short8*)(lK + nbo + dstA) = kApre;
                *(short8*)(lK + nbo + dstB) = kBpre;
                if (kv + 128 < kv_end) {
                    kApre = cvt8(Kf + (size_t)(kv + 128 + kKey0) * D + kD80 * 8);
                    kBpre = cvt8(Kf + (size_t)(kv + 128 + kKey1) * D + kD81 * 8);
                }
            }
        }

        if (kv < wv_end) {
            const bool h1 = (kv + 32 < wv_end);
            const short* Kb = lK + bo;
            const short* Vb = lV + bo;
            // S^T = K Q^T; each kf fragment feeds both q-groups (2x reuse)
            floatx4 zz = (floatx4){0.f,0.f,0.f,0.f};
            floatx4 sA0=zz, sA1=zz, sA2=zz, sA3=zz;
            floatx4 sB0=zz, sB1=zz, sB2=zz, sB3=zz;
            short8 kf;
            __builtin_amdgcn_s_setprio(1);
            kf = ((const short8*)(Kb +    0))[rblk]; sA0 = MFMA16(kf, qA0, sA0); sB0 = MFMA16(kf, qB0, sB0);
            kf = ((const short8*)(Kb +  512))[rblk]; sA0 = MFMA16(kf, qA1, sA0); sB0 = MFMA16(kf, qB1, sB0);
            kf = ((const short8*)(Kb + 1024))[rblk]; sA1 = MFMA16(kf, qA0, sA1); sB1 = MFMA16(kf, qB0, sB1);
            kf = ((const short8*)(Kb + 1536))[rblk]; sA1 = MFMA16(kf, qA1, sA1); sB1 = MFMA16(kf, qB1, sB1);
            if (h1) {
                kf = ((const short8*)(Kb + 2048))[rblk]; sA2 = MFMA16(kf, qA0, sA2); sB2 = MFMA16(kf, qB0, sB2);
                kf = ((const short8*)(Kb + 2560))[rblk]; sA2 = MFMA16(kf, qA1, sA2); sB2 = MFMA16(kf, qB1, sB2);
                kf = ((const short8*)(Kb + 3072))[rblk]; sA3 = MFMA16(kf, qA0, sA3); sB3 = MFMA16(kf, qB0, sB3);
                kf = ((const short8*)(Kb + 3584))[rblk]; sA3 = MFMA16(kf, qA1, sA3); sB3 = MFMA16(kf, qB1, sB3);
            }
            __builtin_amdgcn_s_setprio(0);

            // softmax + P stores: group A (qrow), group B (qrow+16), both halves
            SOFTMAX_STORE(sA0, sA1, qrow,      lPw,        kv);
            SOFTMAX_STORE(sB0, sB1, qrow + 16, lPw + 1024, kv);
            if (h1) {
                SOFTMAX_STORE(sA2, sA3, qrow,      lPw + 512,  kv + 32);
                SOFTMAX_STORE(sB2, sB3, qrow + 16, lPw + 1536, kv + 32);
            }
            LDS_FENCE();                          // lgkm only — vmcnt stays in flight

            // PV: each vf fragment feeds both q-groups (2x reuse)
            short8 pfA = *(const short8*)(lPw + prd);
            short8 pfB = *(const short8*)(lPw + 1024 + prd);
            __builtin_amdgcn_s_setprio(1);
#pragma unroll
            for (int dt = 0; dt < 4; ++dt) {
                short8 vf = ((const short8*)(Vb + dt * 512))[rblk];
                oA[dt] = MFMA16(pfA, vf, oA[dt]);
                oB[dt] = MFMA16(pfB, vf, oB[dt]);
            }
            olA = MFMA16(pfA, ones, olA);
            olB = MFMA16(pfB, ones, olB);
            __builtin_amdgcn_s_setprio(0);
            if (h1) {
                short8 pfA1 = *(const short8*)(lPw + 512 + prd);
                short8 pfB1 = *(const short8*)(lPw + 1536 + prd);
                __builtin_amdgcn_s_setprio(1);
#pragma unroll
                for (int dt = 0; dt < 4; ++dt) {
                    short8 vf = ((const short8*)(Vb + 2048 + dt * 512))[rblk];
                    oA[dt] = MFMA16(pfA1, vf, oA[dt]);
                    oB[dt] = MFMA16(pfB1, vf, oB[dt]);
                }
                olA = MFMA16(pfA1, ones, olA);
                olB = MFMA16(pfB1, ones, olB);
                __builtin_amdgcn_s_setprio(0);
            }
        }
        bo = nbo;
    }
#undef SOFTMAX_STORE

#pragma unroll
    for (int r = 0; r < 4; ++r) {
        const float rl = 1.f / fmaxf(olA[r], 1e-37f);
        const int q = qrow + qd * 4 + r;
        float* op = Og + ((size_t)h * S + q) * D + ll;
#pragma unroll
        for (int dt = 0; dt < 4; ++dt)
            op[dt * 16] = oA[dt][r] * rl;
    }
#pragma unroll
    for (int r = 0; r < 4; ++r) {
        const float rl = 1.f / fmaxf(olB[r], 1e-37f);
        const int q = qrow + 16 + qd * 4 + r;
        float* op = Og + ((size_t)h * S + q) * D + ll;
#pragma unroll
        for (int dt = 0; dt < 4; ++dt)
            op[dt * 16] = oB[dt][r] * rl;
    }
}

// ---- fallback (round-3 verified kernel, no workspace needed) ----
__global__ __launch_bounds__(256, 4)
void attn_legacy(const float* __restrict__ Qg, const float* __restrict__ Kg,
                 const float* __restrict__ Vg, float* __restrict__ Og)
{
    constexpr int S = 4096, D = 64;
    constexpr float SCL2 = 0.125f * 1.44269504088896f;
    constexpr float NEG  = -1.0e30f;
    __shared__ __align__(16) short lK[2048];
    __shared__ __align__(16) short lV[2048];
    __shared__ __align__(16) short lP[2048];
    const int tid = threadIdx.x, wv = tid >> 6, ln = tid & 63, ll = ln & 15, qd = ln >> 4;
    const int bid = blockIdx.x, h = bid & 15, qblk = 63 - (bid >> 4), qb = qblk << 6;
    const float* Qh = Qg + (size_t)h * S * D;
    const float* Kh = Kg + (size_t)h * S * D;
    const float* Vh = Vg + (size_t)h * S * D;
    const int qrow = qb + wv * 16;
    short8 qf0, qf1;
    { const float* qp = Qh + (qrow + ll) * D + qd * 8; qf0 = cvt8(qp); qf1 = cvt8(qp + 32); }
    floatx4 o[4]; float mi[4], li[4];
#pragma unroll
    for (int dt = 0; dt < 4; ++dt) o[dt] = (floatx4){0.f,0.f,0.f,0.f};
#pragma unroll
    for (int r = 0; r < 4; ++r) { mi[r] = NEG; li[r] = 0.f; }
    const int k_st = tid >> 3, dbase = (tid & 7) * 8;
    const int sq = (dbase >> 3) & 3, sks = dbase >> 5;
    const int kw_slot = (((k_st >> 4) * 2 + sks) * 64)
                      + (((sq << 4) | (k_st & 15)) ^ (sq | (sks << 2)));
    const int kr0 = ln ^ qd, kr1 = ln ^ (qd | 4), vbit3 = (ln >> 3) & 1;
    const int kv_end = qb + 64, wv_end = qrow + 16;
    for (int kv = 0; kv < kv_end; kv += 32) {
        __syncthreads();
        {
            short8 kval = cvt8(Kh + (kv + k_st) * D + dbase);
            ((short8*)lK)[kw_slot] = kval;
            short8 vval = cvt8(Vh + (kv + k_st) * D + dbase);
            const int vq = (k_st >> 3) << 4, vj = k_st & 7;
#pragma unroll
            for (int i = 0; i < 8; ++i) {
                int d = dbase + i, dt = d >> 4, l2 = d & 15;
                int lp = (vq | l2) ^ (((l2 >> 3) & 1) | (dt << 1));
                lV[dt * 512 + lp * 8 + vj] = vval[i];
            }
        }
        __syncthreads();
        if (kv < wv_end) {
            floatx4 sc0 = (floatx4){0.f,0.f,0.f,0.f}, sc1 = sc0; short8 kf;
            kf = ((const short8*)lK)[0*64+kr0]; sc0 = MFMA16(qf0, kf, sc0);
            kf = ((const short8*)lK)[1*64+kr1]; sc0 = MFMA16(qf1, kf, sc0);
            kf = ((const short8*)lK)[2*64+kr0]; sc1 = MFMA16(qf0, kf, sc1);
            kf = ((const short8*)lK)[3*64+kr1]; sc1 = MFMA16(qf1, kf, sc1);
            float p0[4], p1[4]; const int qg = qrow + qd * 4;
#pragma unroll
            for (int r = 0; r < 4; ++r) { p0[r] = sc0[r]*SCL2; p1[r] = sc1[r]*SCL2; }
            if (kv + 31 > qrow) {
                const int k0 = kv + ll, k1 = kv + 16 + ll;
#pragma unroll
                for (int r = 0; r < 4; ++r) {
                    if (k0 > qg + r) p0[r] = NEG;
                    if (k1 > qg + r) p1[r] = NEG;
                }
            }
#pragma unroll
            for (int r = 0; r < 4; ++r) {
                float mx = fmaxf(p0[r], p1[r]);
                mx = fmaxf(mx, __shfl_xor(mx,1)); mx = fmaxf(mx, __shfl_xor(mx,2));
                mx = fmaxf(mx, __shfl_xor(mx,4)); mx = fmaxf(mx, __shfl_xor(mx,8));
                const float nm = fmaxf(mi[r], mx);
                const float a = exp2f(mi[r] - nm); mi[r] = nm;
                p0[r] = exp2f(p0[r] - nm); p1[r] = exp2f(p1[r] - nm);
                float ps = p0[r] + p1[r];
                ps += __shfl_xor(ps,1); ps += __shfl_xor(ps,2);
                ps += __shfl_xor(ps,4); ps += __shfl_xor(ps,8);
                li[r] = li[r] * a + ps;
#pragma unroll
                for (int dt = 0; dt < 4; ++dt) o[dt][r] *= a;
            }
            {
                const int pbase = wv * 512 + (ll & 7);
                const int dl0 = ((ll >> 3) << 4) + qd * 4;
#pragma unroll
                for (int r = 0; r < 4; ++r) {
                    lP[pbase + (dl0 + r) * 8]      = bf16bits(p0[r]);
                    lP[pbase + (dl0 + 32 + r) * 8] = bf16bits(p1[r]);
                }
            }
            __threadfence_block();
            short8 pf = ((const short8*)lP)[wv * 64 + ln];
#pragma unroll
            for (int dt = 0; dt < 4; ++dt) {
                short8 vf = ((const short8*)lV)[dt * 64 + (ln ^ (vbit3 | (dt << 1)))];
                o[dt] = MFMA16(pf, vf, o[dt]);
            }
        }
    }
#pragma unroll
    for (int r = 0; r < 4; ++r) {
        const float rl = 1.f / fmaxf(li[r], 1e-30f);
        const int q = qrow + qd * 4 + r;
        float* op = Og + ((size_t)h * S + q) * D + ll;
#pragma unroll
        for (int dt = 0; dt < 4; ++dt) op[dt * 16] = o[dt][r] * rl;
    }
}

extern "C" void kernel_launch(void* const* d_in, const int* in_sizes, int n_in,
                              void* d_out, int out_size, void* d_ws, size_t ws_size,
                              hipStream_t stream) {
    const float* Q = (const float*)d_in[0];
    const float* K = (const float*)d_in[1];
    const float* V = (const float*)d_in[2];
    float* O = (float*)d_out;
    const size_t elems  = (size_t)16 * 4096 * 64;
    const size_t oneBuf = elems * sizeof(short);          // 8.39 MB
    if (ws_size >= 2 * oneBuf) {
        short* VT  = (short*)d_ws;
        short* K16 = (short*)d_ws + elems;
        prep<<<dim3(1024), dim3(256), 0, stream>>>(V, VT, K, K16, 1);
        attn_fast<true><<<dim3(512), dim3(256), 0, stream>>>(Q, K, K16, VT, O);
    } else if (ws_size >= oneBuf) {
        short* VT = (short*)d_ws;
        prep<<<dim3(1024), dim3(256), 0, stream>>>(V, VT, K, VT, 0);
        attn_fast<false><<<dim3(512), dim3(256), 0, stream>>>(Q, K, nullptr, VT, O);
    } else {
        attn_legacy<<<dim3(1024), dim3(256), 0, stream>>>(Q, K, V, O);
    }
}

// Round 4
// 193.116 us; speedup vs baseline: 1.3077x; 1.3077x over previous
//
#include <hip/hip_runtime.h>
#include <hip/hip_bf16.h>

typedef __attribute__((ext_vector_type(8))) short short8;
typedef __attribute__((ext_vector_type(4))) short s4v;
typedef __attribute__((ext_vector_type(2))) int   int2v;
typedef __attribute__((ext_vector_type(4))) int   int4v;
typedef __attribute__((ext_vector_type(4))) float floatx4;

#define MFMA16(A,B,C) __builtin_amdgcn_mfma_f32_16x16x32_bf16(A,B,C,0,0,0)

__device__ __forceinline__ short bf16bits(float x) {
    __hip_bfloat16 h = __float2bfloat16(x);
    return *(short*)&h;
}
__device__ __forceinline__ short8 cvt8(const float* p) {
    floatx4 a = *(const floatx4*)p;
    floatx4 b = *(const floatx4*)(p + 4);
    short8 r;
    r[0]=bf16bits(a.x); r[1]=bf16bits(a.y); r[2]=bf16bits(a.z); r[3]=bf16bits(a.w);
    r[4]=bf16bits(b.x); r[5]=bf16bits(b.y); r[6]=bf16bits(b.z); r[7]=bf16bits(b.w);
    return r;
}
// scaled variant for Q: folds 1/sqrt(d) * log2(e) so softmax is a bare v_exp_f32
__device__ __forceinline__ short8 cvt8s(const float* p) {
    constexpr float SCL2 = 0.125f * 1.44269504088896f;
    floatx4 a = *(const floatx4*)p;
    floatx4 b = *(const floatx4*)(p + 4);
    a *= SCL2; b *= SCL2;
    short8 r;
    r[0]=bf16bits(a.x); r[1]=bf16bits(a.y); r[2]=bf16bits(a.z); r[3]=bf16bits(a.w);
    r[4]=bf16bits(b.x); r[5]=bf16bits(b.y); r[6]=bf16bits(b.z); r[7]=bf16bits(b.w);
    return r;
}
// hardware packed f32->bf16 (RNE, identical rounding to __float2bfloat16)
__device__ __forceinline__ int pk2(float lo, float hi) {
    int r;
    asm("v_cvt_pk_bf16_f32 %0, %1, %2" : "=v"(r) : "v"(lo), "v"(hi));
    return r;
}

// ---- prologue (fused): V -> VT [h][d][s] bf16, and K -> K16 bf16 row-major ----
__global__ __launch_bounds__(256) void prep(const float* __restrict__ V,
                                            short* __restrict__ VT,
                                            const float* __restrict__ K,
                                            short* __restrict__ K16, int doK)
{
    __shared__ short tile[64 * 65];
    const int t  = threadIdx.x;
    const int h  = blockIdx.x >> 6;
    const int s0 = (blockIdx.x & 63) << 6;
    const float* src = V + ((size_t)h * 4096 + s0) * 64;
    const int r = t >> 4, dq = (t & 15) * 4;
#pragma unroll
    for (int pass = 0; pass < 4; ++pass) {
        const int s = pass * 16 + r;
        floatx4 f = *(const floatx4*)(src + s * 64 + dq);
        short* w = tile + s * 65 + dq;
        w[0] = bf16bits(f.x); w[1] = bf16bits(f.y);
        w[2] = bf16bits(f.z); w[3] = bf16bits(f.w);
    }
    __syncthreads();
    const int d = t >> 2, sc = (t & 3) * 16;
    short8 a, b;
#pragma unroll
    for (int j = 0; j < 8; ++j) a[j] = tile[(sc + j) * 65 + d];
#pragma unroll
    for (int j = 0; j < 8; ++j) b[j] = tile[(sc + 8 + j) * 65 + d];
    short* dst = VT + ((size_t)h * 64 + d) * 4096 + s0 + sc;
    *(short8*)dst       = a;
    *(short8*)(dst + 8) = b;
    if (doK) {
        const size_t base = (size_t)blockIdx.x * 4096 + (size_t)t * 16;
        *(short8*)(K16 + base)     = cvt8(K + base);
        *(short8*)(K16 + base + 8) = cvt8(K + base + 8);
    }
}

// ---- main (R1 structure + in-register P via permlane swaps) ----
// 4 waves x 16q, 64-key tiles, 1024 blocks, balanced qblk mapping.
// P never touches LDS: the 4x4 dword permutation (qd-rows x w-regs) ->
// PV A-fragment is done by 2x v_permlane32_swap + 2x v_permlane16_swap.
template<bool KB16>
__global__ __launch_bounds__(256, 4)
void attn_fast(const float* __restrict__ Qg, const float* __restrict__ Kg,
               const short* __restrict__ K16g, const short* __restrict__ VTg,
               float* __restrict__ Og)
{
    constexpr int S = 4096, D = 64;

    __shared__ __align__(16) short lK[4096];   // 64 keys x 64 d (swizzled)
    __shared__ __align__(16) short lV[4096];   // 64 d x 64 keys (from VT, swizzled)

    const int tid = threadIdx.x;
    const int wv  = tid >> 6;
    const int ln  = tid & 63;
    const int ll  = ln & 15;
    const int qd  = ln >> 4;

    // balanced qblk mapping: per-CU sets {63-x, 32+x, 31-x, x}
    const int c = blockIdx.x & 255;
    const int s = blockIdx.x >> 8;
    const int h = c & 15;
    const int x = c >> 4;
    const int qblk = (s == 0) ? (63 - x) : (s == 1) ? (32 + x) : (s == 2) ? (31 - x) : x;
    const int qb   = qblk << 6;
    const int qrow = qb + wv * 16;

    const float* Qh  = Qg  + (size_t)h * S * D;
    const float* Kf  = Kg  + (size_t)h * S * D;
    const short* K16 = K16g + (size_t)h * S * D;
    const short* Vt  = VTg + (size_t)h * 64 * S;

    short8 qf0, qf1;     // Q pre-scaled by 1/sqrt(64)*log2(e)
    {
        const float* qp = Qh + (qrow + ll) * D + qd * 8;
        qf0 = cvt8s(qp);
        qf1 = cvt8s(qp + 32);
    }

    floatx4 o[4], ol;
#pragma unroll
    for (int dt = 0; dt < 4; ++dt) o[dt] = (floatx4){0.f, 0.f, 0.f, 0.f};
    ol = (floatx4){0.f, 0.f, 0.f, 0.f};

    short8 ones;
#pragma unroll
    for (int j = 0; j < 8; ++j) ones[j] = (short)0x3F80;  // bf16 1.0

    // K staging: thread t -> key=t>>3 (0..31) within half, d-octet=t&7
    const int kkey = tid >> 3, kd8 = tid & 7;
    const int koct = kd8 & 3;
    short* kdst = lK + ((kkey >> 4) * 2 + (kd8 >> 2)) * 512
                     + ((((kkey & 15) | (koct << 4)) ^ (koct * 5)) * 8);
    const float* ksrcf = Kf  + kkey * 64 + kd8 * 8;
    const short* ksrc6 = K16 + kkey * 64 + kd8 * 8;
    // V staging: thread t -> d=t>>2 (0..63), key-octet=t&3 (from VT)
    const int vd = tid >> 2, voct = tid & 3;
    short* vdst = lV + (vd >> 4) * 512
                     + ((((vd & 15) | (voct << 4)) ^ (voct * 5)) * 8);
    const short* vsrc = Vt + (size_t)vd * S + voct * 8;
    // fragment read block (lK / lV)
    const int rblk = ((ll | (qd << 4)) ^ (qd * 5));

    const int kv_end = qb + 64;
    const int wv_end = qrow + 16;

    auto ldK = [&](int kv) -> short8 {
        return KB16 ? *(const short8*)(ksrc6 + kv * 64) : cvt8(ksrcf + kv * 64);
    };

    // softmax + in-register P->A-fragment transpose (no LDS):
    // source: lane(ll,qd) dword w_b holds keys 16*(b>>1)+4*qd+2*(b&1)+{0,1}
    // target: lane(ll,qd') dword j holds keys 8*qd'+2j+{0,1}
    // factorization: P32(w0,w2), P32(w1,w3), P16(w0,w2), P16(w1,w3)
    auto mkpf = [&](floatx4 sc0, floatx4 sc1, int kvh) -> short8 {
        float p0[4], p1[4];
#pragma unroll
        for (int r = 0; r < 4; ++r) { p0[r] = exp2f(sc0[r]); p1[r] = exp2f(sc1[r]); }
        if (kvh + 31 > qrow) {                 // diagonal tiles only
            const int qg = qrow + ll;
            const int k0 = kvh + qd * 4, k1 = k0 + 16;
#pragma unroll
            for (int r = 0; r < 4; ++r) {
                if (k0 + r > qg) p0[r] = 0.f;
                if (k1 + r > qg) p1[r] = 0.f;
            }
        }
        int w0 = pk2(p0[0], p0[1]);
        int w1 = pk2(p0[2], p0[3]);
        int w2 = pk2(p1[0], p1[1]);
        int w3 = pk2(p1[2], p1[3]);
        asm("v_permlane32_swap_b32 %0, %1" : "+v"(w0), "+v"(w2));
        asm("v_permlane32_swap_b32 %0, %1" : "+v"(w1), "+v"(w3));
        asm("v_permlane16_swap_b32 %0, %1" : "+v"(w0), "+v"(w2));
        asm("v_permlane16_swap_b32 %0, %1" : "+v"(w1), "+v"(w3));
        int4v pv = {w0, w1, w2, w3};
        return *(short8*)&pv;
    };

    short8 kpre0 = ldK(0),  kpre1 = ldK(32);
    short8 vpre0 = *(const short8*)(vsrc);
    short8 vpre1 = *(const short8*)(vsrc + 32);

    for (int kv = 0; kv < kv_end; kv += 64) {
        __syncthreads();
        *(short8*)kdst          = kpre0;
        *(short8*)(kdst + 2048) = kpre1;
        *(short8*)vdst          = vpre0;
        *(short8*)(vdst + 2048) = vpre1;
        __syncthreads();
        if (kv + 64 < kv_end) {            // prefetch next tile; stays in flight
            kpre0 = ldK(kv + 64);
            kpre1 = ldK(kv + 96);
            vpre0 = *(const short8*)(vsrc + kv + 64);
            vpre1 = *(const short8*)(vsrc + kv + 96);
        }

        if (kv < wv_end) {
            const bool h1 = (kv + 32 < wv_end);
            // S^T = K Q^T (operand swap; A/B frag layouts identical)
            floatx4 zz = (floatx4){0.f, 0.f, 0.f, 0.f};
            floatx4 sc0 = zz, sc1 = zz, sc2 = zz, sc3 = zz;
            short8 kf;
            __builtin_amdgcn_s_setprio(1);
            kf = ((const short8*)(lK +    0))[rblk]; sc0 = MFMA16(kf, qf0, sc0);
            kf = ((const short8*)(lK +  512))[rblk]; sc0 = MFMA16(kf, qf1, sc0);
            kf = ((const short8*)(lK + 1024))[rblk]; sc1 = MFMA16(kf, qf0, sc1);
            kf = ((const short8*)(lK + 1536))[rblk]; sc1 = MFMA16(kf, qf1, sc1);
            if (h1) {
                kf = ((const short8*)(lK + 2048))[rblk]; sc2 = MFMA16(kf, qf0, sc2);
                kf = ((const short8*)(lK + 2560))[rblk]; sc2 = MFMA16(kf, qf1, sc2);
                kf = ((const short8*)(lK + 3072))[rblk]; sc3 = MFMA16(kf, qf0, sc3);
                kf = ((const short8*)(lK + 3584))[rblk]; sc3 = MFMA16(kf, qf1, sc3);
            }
            __builtin_amdgcn_s_setprio(0);

            // half 0: softmax -> in-reg P fragment -> PV
            short8 pf0 = mkpf(sc0, sc1, kv);
            __builtin_amdgcn_s_setprio(1);
#pragma unroll
            for (int dt = 0; dt < 4; ++dt) {
                short8 vf = ((const short8*)(lV + dt * 512))[rblk];
                o[dt] = MFMA16(pf0, vf, o[dt]);
            }
            ol = MFMA16(pf0, ones, ol);            // row-sums
            __builtin_amdgcn_s_setprio(0);
            if (h1) {
                short8 pf1 = mkpf(sc2, sc3, kv + 32);
                __builtin_amdgcn_s_setprio(1);
#pragma unroll
                for (int dt = 0; dt < 4; ++dt) {
                    short8 vf = ((const short8*)(lV + 2048 + dt * 512))[rblk];
                    o[dt] = MFMA16(pf1, vf, o[dt]);
                }
                ol = MFMA16(pf1, ones, ol);
                __builtin_amdgcn_s_setprio(0);
            }
        }
    }

#pragma unroll
    for (int r = 0; r < 4; ++r) {
        const float rl = 1.f / fmaxf(ol[r], 1e-37f);
        const int q = qrow + qd * 4 + r;
        float* op = Og + ((size_t)h * S + q) * D + ll;
#pragma unroll
        for (int dt = 0; dt < 4; ++dt)
            op[dt * 16] = o[dt][r] * rl;
    }
}

// ---- fallback (round-3 verified kernel, no workspace needed) ----
__global__ __launch_bounds__(256, 4)
void attn_legacy(const float* __restrict__ Qg, const float* __restrict__ Kg,
                 const float* __restrict__ Vg, float* __restrict__ Og)
{
    constexpr int S = 4096, D = 64;
    constexpr float SCL2 = 0.125f * 1.44269504088896f;
    constexpr float NEG  = -1.0e30f;
    __shared__ __align__(16) short lK[2048];
    __shared__ __align__(16) short lV[2048];
    __shared__ __align__(16) short lP[2048];
    const int tid = threadIdx.x, wv = tid >> 6, ln = tid & 63, ll = ln & 15, qd = ln >> 4;
    const int bid = blockIdx.x, h = bid & 15, qblk = 63 - (bid >> 4), qb = qblk << 6;
    const float* Qh = Qg + (size_t)h * S * D;
    const float* Kh = Kg + (size_t)h * S * D;
    const float* Vh = Vg + (size_t)h * S * D;
    const int qrow = qb + wv * 16;
    short8 qf0, qf1;
    { const float* qp = Qh + (qrow + ll) * D + qd * 8; qf0 = cvt8(qp); qf1 = cvt8(qp + 32); }
    floatx4 o[4]; float mi[4], li[4];
#pragma unroll
    for (int dt = 0; dt < 4; ++dt) o[dt] = (floatx4){0.f,0.f,0.f,0.f};
#pragma unroll
    for (int r = 0; r < 4; ++r) { mi[r] = NEG; li[r] = 0.f; }
    const int k_st = tid >> 3, dbase = (tid & 7) * 8;
    const int sq = (dbase >> 3) & 3, sks = dbase >> 5;
    const int kw_slot = (((k_st >> 4) * 2 + sks) * 64)
                      + (((sq << 4) | (k_st & 15)) ^ (sq | (sks << 2)));
    const int kr0 = ln ^ qd, kr1 = ln ^ (qd | 4), vbit3 = (ln >> 3) & 1;
    const int kv_end = qb + 64, wv_end = qrow + 16;
    for (int kv = 0; kv < kv_end; kv += 32) {
        __syncthreads();
        {
            short8 kval = cvt8(Kh + (kv + k_st) * D + dbase);
            ((short8*)lK)[kw_slot] = kval;
            short8 vval = cvt8(Vh + (kv + k_st) * D + dbase);
            const int vq = (k_st >> 3) << 4, vj = k_st & 7;
#pragma unroll
            for (int i = 0; i < 8; ++i) {
                int d = dbase + i, dt = d >> 4, l2 = d & 15;
                int lp = (vq | l2) ^ (((l2 >> 3) & 1) | (dt << 1));
                lV[dt * 512 + lp * 8 + vj] = vval[i];
            }
        }
        __syncthreads();
        if (kv < wv_end) {
            floatx4 sc0 = (floatx4){0.f,0.f,0.f,0.f}, sc1 = sc0; short8 kf;
            kf = ((const short8*)lK)[0*64+kr0]; sc0 = MFMA16(qf0, kf, sc0);
            kf = ((const short8*)lK)[1*64+kr1]; sc0 = MFMA16(qf1, kf, sc0);
            kf = ((const short8*)lK)[2*64+kr0]; sc1 = MFMA16(qf0, kf, sc1);
            kf = ((const short8*)lK)[3*64+kr1]; sc1 = MFMA16(qf1, kf, sc1);
            float p0[4], p1[4]; const int qg = qrow + qd * 4;
#pragma unroll
            for (int r = 0; r < 4; ++r) { p0[r] = sc0[r]*SCL2; p1[r] = sc1[r]*SCL2; }
            if (kv + 31 > qrow) {
                const int k0 = kv + ll, k1 = kv + 16 + ll;
#pragma unroll
                for (int r = 0; r < 4; ++r) {
                    if (k0 > qg + r) p0[r] = NEG;
                    if (k1 > qg + r) p1[r] = NEG;
                }
            }
#pragma unroll
            for (int r = 0; r < 4; ++r) {
                float mx = fmaxf(p0[r], p1[r]);
                mx = fmaxf(mx, __shfl_xor(mx,1)); mx = fmaxf(mx, __shfl_xor(mx,2));
                mx = fmaxf(mx, __shfl_xor(mx,4)); mx = fmaxf(mx, __shfl_xor(mx,8));
                const float nm = fmaxf(mi[r], mx);
                const float a = exp2f(mi[r] - nm); mi[r] = nm;
                p0[r] = exp2f(p0[r] - nm); p1[r] = exp2f(p1[r] - nm);
                float ps = p0[r] + p1[r];
                ps += __shfl_xor(ps,1); ps += __shfl_xor(ps,2);
                ps += __shfl_xor(ps,4); ps += __shfl_xor(ps,8);
                li[r] = li[r] * a + ps;
#pragma unroll
                for (int dt = 0; dt < 4; ++dt) o[dt][r] *= a;
            }
            {
                const int pbase = wv * 512 + (ll & 7);
                const int dl0 = ((ll >> 3) << 4) + qd * 4;
#pragma unroll
                for (int r = 0; r < 4; ++r) {
                    lP[pbase + (dl0 + r) * 8]      = bf16bits(p0[r]);
                    lP[pbase + (dl0 + 32 + r) * 8] = bf16bits(p1[r]);
                }
            }
            __threadfence_block();
            short8 pf = ((const short8*)lP)[wv * 64 + ln];
#pragma unroll
            for (int dt = 0; dt < 4; ++dt) {
                short8 vf = ((const short8*)lV)[dt * 64 + (ln ^ (vbit3 | (dt << 1)))];
                o[dt] = MFMA16(pf, vf, o[dt]);
            }
        }
    }
#pragma unroll
    for (int r = 0; r < 4; ++r) {
        const float rl = 1.f / fmaxf(li[r], 1e-30f);
        const int q = qrow + qd * 4 + r;
        float* op = Og + ((size_t)h * S + q) * D + ll;
#pragma unroll
        for (int dt = 0; dt < 4; ++dt) op[dt * 16] = o[dt][r] * rl;
    }
}

extern "C" void kernel_launch(void* const* d_in, const int* in_sizes, int n_in,
                              void* d_out, int out_size, void* d_ws, size_t ws_size,
                              hipStream_t stream) {
    const float* Q = (const float*)d_in[0];
    const float* K = (const float*)d_in[1];
    const float* V = (const float*)d_in[2];
    float* O = (float*)d_out;
    const size_t elems  = (size_t)16 * 4096 * 64;
    const size_t oneBuf = elems * sizeof(short);          // 8.39 MB
    if (ws_size >= 2 * oneBuf) {
        short* VT  = (short*)d_ws;
        short* K16 = (short*)d_ws + elems;
        prep<<<dim3(1024), dim3(256), 0, stream>>>(V, VT, K, K16, 1);
        attn_fast<true><<<dim3(1024), dim3(256), 0, stream>>>(Q, K, K16, VT, O);
    } else if (ws_size >= oneBuf) {
        short* VT = (short*)d_ws;
        prep<<<dim3(1024), dim3(256), 0, stream>>>(V, VT, K, VT, 0);
        attn_fast<false><<<dim3(1024), dim3(256), 0, stream>>>(Q, K, nullptr, VT, O);
    } else {
        attn_legacy<<<dim3(1024), dim3(256), 0, stream>>>(Q, K, V, O);
    }
}